// Round 1
// baseline (41000.635 us; speedup 1.0000x reference)
//
#include <hip/hip_runtime.h>

// CVRAE forward: B=256, S=512, A=64, H=1024, Z=256.
// Strategy: bf16 MFMA (16x16x32) for all GEMMs, fp32 master state for h,
// one-hot px collapsed to precomputed tables, 4 phase-kernels per step.

typedef float f32x4 __attribute__((ext_vector_type(4)));
typedef __bf16 bf16x8 __attribute__((ext_vector_type(8)));

#define BB 256
#define SS 512
#define HH 1024
#define ZZ 256
#define AA 64

__device__ __forceinline__ float softplus_(float x) {
    return (x > 15.f) ? x : log1pf(expf(x));
}
__device__ __forceinline__ float sigmoid_(float x) {
    return 1.f / (1.f + expf(-x));
}

// Wave-level row tile GEMM: out[16 x 16*NT] += A[16 x K] * W[16*NT x K]^T
// A layout row-major [*, lda], W row-major [*, ldb]. K multiple of 32.
template<int NT>
__device__ __forceinline__ void gemm_rowtile(const __bf16* __restrict__ A, int lda,
                                             const __bf16* __restrict__ W, int ldb,
                                             int K, f32x4* acc) {
    int lane = threadIdx.x & 63;
    int rr = lane & 15;
    int ko = (lane >> 4) * 8;
    const __bf16* ap = A + rr * lda + ko;
    const __bf16* bp = W + rr * ldb + ko;
    #pragma unroll 4
    for (int k = 0; k < K; k += 32) {
        bf16x8 af = *(const bf16x8*)(ap + k);
        #pragma unroll
        for (int t = 0; t < NT; t++) {
            bf16x8 bf = *(const bf16x8*)(bp + t * 16 * ldb + k);
            acc[t] = __builtin_amdgcn_mfma_f32_16x16x32_bf16(af, bf, acc[t], 0, 0, 0);
        }
    }
}

// ---------------- prep kernels ----------------

__global__ void k_zero(float* p) { *p = 0.f; }

__global__ void k_finkld(const float* kld, float* out) { *out = *kld; }

__global__ void k_pack(const float* __restrict__ src, int src_ld, int col_off,
                       __bf16* __restrict__ dst, int cols, int total) {
    int i = blockIdx.x * 256 + threadIdx.x;
    if (i >= total) return;
    int r = i / cols, c = i - r * cols;
    dst[i] = (__bf16)src[r * src_ld + col_off + c];
}

__global__ void k_copyf(const float* __restrict__ s, float* __restrict__ d, int n) {
    int i = blockIdx.x * 256 + threadIdx.x;
    if (i < n) d[i] = s[i];
}

// px[a][h] = relu(phi_x_w[h][a] + phi_x_b[h]), fp32 [64,1024]
__global__ void k_px(const float* __restrict__ phi_x_w, const float* __restrict__ phi_x_b,
                     float* __restrict__ px) {
    int i = blockIdx.x * 256 + threadIdx.x;  // 64*1024
    int a = i >> 10, hh = i & 1023;
    px[i] = fmaxf(phi_x_w[hh * AA + a] + phi_x_b[hh], 0.f);
}

// encpx[a][n] = sum_k enc_w1[n][k] * px[a][k]  (n<1024, k<1024, enc_w1 ld=2048)
// gipx[a][g]  = sum_k gru_wih[g][k] * px[a][k] (g<3072, wih ld=2048)
__global__ __launch_bounds__(256) void k_tables(const float* __restrict__ enc_w1,
                                                const float* __restrict__ wih,
                                                const float* __restrict__ px,
                                                float* __restrict__ encpx,
                                                float* __restrict__ gipx) {
    __shared__ float spx[64][65];
    int tid = threadIdx.x;
    int cg = blockIdx.x * 4 + (tid >> 6);
    int a = tid & 63;
    const float* wrow = (cg < 1024) ? (enc_w1 + cg * 2048) : (wih + (cg - 1024) * 2048);
    float sum = 0.f;
    for (int k0 = 0; k0 < 1024; k0 += 64) {
        __syncthreads();
        for (int e = tid; e < 4096; e += 256)
            spx[e >> 6][e & 63] = px[((e >> 6) << 10) + k0 + (e & 63)];
        __syncthreads();
        #pragma unroll 8
        for (int kk = 0; kk < 64; kk++) sum += wrow[k0 + kk] * spx[a][kk];
    }
    if (cg < 1024) encpx[a * 1024 + cg] = sum;
    else gipx[a * 3072 + (cg - 1024)] = sum;
}

// ---------------- per-step phase kernels ----------------

// Phase A: hidcat[b, 0:1024]   = relu(h @ enc_w1_h.T + encpx[x_b] + enc_b1)
//          hidcat[b, 1024:2048]= relu(h @ pri_w1.T + pri_b1)
// WA: [2048, 1024] bf16 (rows 0..1023 = enc_w1 h-half, 1024..2047 = pri_w1)
__global__ __launch_bounds__(256) void k_phaseA(const __bf16* __restrict__ hb,
                                                const __bf16* __restrict__ WA,
                                                const float* __restrict__ eb1,
                                                const float* __restrict__ pb1,
                                                const float* __restrict__ encpx,
                                                const int* __restrict__ x, int t,
                                                __bf16* __restrict__ hidcat) {
    int n0 = blockIdx.x * 64, m0 = blockIdx.y * 32;
    int w = threadIdx.x >> 6, lane = threadIdx.x & 63;
    int mt = m0 + (w & 1) * 16, nt = n0 + (w >> 1) * 32;
    f32x4 acc[2] = {{0.f,0.f,0.f,0.f},{0.f,0.f,0.f,0.f}};
    gemm_rowtile<2>(hb + mt * HH, HH, WA + nt * HH, HH, HH, acc);
    int col = lane & 15, rq = (lane >> 4) * 4;
    #pragma unroll
    for (int tt = 0; tt < 2; tt++) {
        int n = nt + tt * 16 + col;
        float bias = (n < 1024) ? eb1[n] : pb1[n - 1024];
        #pragma unroll
        for (int i = 0; i < 4; i++) {
            int m = mt + rq + i;
            float v = acc[tt][i] + bias;
            if (n < 1024) v += encpx[x[m * SS + t] * 1024 + n];
            v = fmaxf(v, 0.f);
            hidcat[m * 2048 + n] = (__bf16)v;
        }
    }
}

// Phase B: enc/pri [B,Z], kld accumulation, z sample -> zbuf bf16
// W2: [512, 1024] bf16 (rows 0..255 enc_w2, 256..511 pri_w2)
__global__ __launch_bounds__(256) void k_phaseB(const __bf16* __restrict__ hidcat,
                                                const __bf16* __restrict__ W2,
                                                const float* __restrict__ eb2,
                                                const float* __restrict__ pb2,
                                                const float* __restrict__ eps_t,
                                                __bf16* __restrict__ zbuf,
                                                float* __restrict__ kld) {
    int z0 = blockIdx.x * 32, m0 = blockIdx.y * 32;
    int w = threadIdx.x >> 6, lane = threadIdx.x & 63;
    int mt = m0 + (w & 1) * 16, zt = z0 + (w >> 1) * 16;
    f32x4 ae = {0.f,0.f,0.f,0.f}, ap = {0.f,0.f,0.f,0.f};
    gemm_rowtile<1>(hidcat + mt * 2048, 2048, W2 + zt * HH, HH, HH, &ae);
    gemm_rowtile<1>(hidcat + mt * 2048 + 1024, 2048, W2 + (256 + zt) * HH, HH, HH, &ap);
    int col = lane & 15, rq = (lane >> 4) * 4;
    int z = zt + col;
    float be = eb2[z], bp = pb2[z];
    float kl = 0.f;
    #pragma unroll
    for (int i = 0; i < 4; i++) {
        int m = mt + rq + i;
        float enc = ae[i] + be;
        float pri = ap[i] + bp;
        float es = softplus_(enc), ps = softplus_(pri);
        float d = enc - pri;
        kl += 2.f * (logf(ps) - logf(es)) + (es * es + d * d) / (ps * ps) - 1.f;
        float zv = eps_t[m * ZZ + z] * es + enc;
        zbuf[m * ZZ + z] = (__bf16)zv;
    }
    #pragma unroll
    for (int off = 1; off < 64; off <<= 1) kl += __shfl_xor(kl, off);
    if (lane == 0) atomicAdd(kld, 0.5f * kl);
}

// Generic GEMM: out[m,n] = act(A[m,:K] . W[n,:K] + bias[n])
template<bool RELU, bool OUT_BF16>
__global__ __launch_bounds__(256) void k_gemm(const __bf16* __restrict__ A, int lda,
                                              const __bf16* __restrict__ W, int ldb,
                                              const float* __restrict__ bias,
                                              void* __restrict__ out, int ldo, int K) {
    int n0 = blockIdx.x * 64, m0 = blockIdx.y * 32;
    int w = threadIdx.x >> 6, lane = threadIdx.x & 63;
    int mt = m0 + (w & 1) * 16, nt = n0 + (w >> 1) * 32;
    f32x4 acc[2] = {{0.f,0.f,0.f,0.f},{0.f,0.f,0.f,0.f}};
    gemm_rowtile<2>(A + mt * lda, lda, W + nt * ldb, ldb, K, acc);
    int col = lane & 15, rq = (lane >> 4) * 4;
    #pragma unroll
    for (int tt = 0; tt < 2; tt++) {
        int n = nt + tt * 16 + col;
        float b = bias[n];
        #pragma unroll
        for (int i = 0; i < 4; i++) {
            int m = mt + rq + i;
            float v = acc[tt][i] + b;
            if (RELU) v = fmaxf(v, 0.f);
            if (OUT_BF16) ((__bf16*)out)[m * ldo + n] = (__bf16)v;
            else ((float*)out)[m * ldo + n] = v;
        }
    }
}

// Phase D: GRU cell. gi (from pz) + gipx table + bih; gh (from h) + bhh; gates; h_new.
__global__ __launch_bounds__(256) void k_phaseD(const __bf16* __restrict__ pz,
                                                const __bf16* __restrict__ hb,
                                                const __bf16* __restrict__ wih_pz,
                                                const __bf16* __restrict__ whh,
                                                const float* __restrict__ gipx,
                                                const float* __restrict__ bih,
                                                const float* __restrict__ bhh,
                                                const int* __restrict__ x, int t,
                                                const float* __restrict__ h_old,
                                                float* __restrict__ h_new,
                                                __bf16* __restrict__ hb_new) {
    int j0 = blockIdx.x * 32, m0 = blockIdx.y * 32;
    int w = threadIdx.x >> 6, lane = threadIdx.x & 63;
    int mt = m0 + (w & 1) * 16, jt = j0 + (w >> 1) * 16;
    int rr = lane & 15, ko = (lane >> 4) * 8;
    const __bf16* apz = pz + (mt + rr) * HH + ko;
    const __bf16* ah  = hb + (mt + rr) * HH + ko;
    const __bf16* wir = wih_pz + (jt + rr) * HH + ko;
    const __bf16* wiz = wih_pz + (1024 + jt + rr) * HH + ko;
    const __bf16* win = wih_pz + (2048 + jt + rr) * HH + ko;
    const __bf16* whr = whh + (jt + rr) * HH + ko;
    const __bf16* whz = whh + (1024 + jt + rr) * HH + ko;
    const __bf16* whn = whh + (2048 + jt + rr) * HH + ko;
    f32x4 air = {0.f,0.f,0.f,0.f}, aiz = air, ain = air, ahr = air, ahz = air, ahn = air;
    #pragma unroll 2
    for (int k = 0; k < HH; k += 32) {
        bf16x8 fpz = *(const bf16x8*)(apz + k);
        bf16x8 fh  = *(const bf16x8*)(ah + k);
        air = __builtin_amdgcn_mfma_f32_16x16x32_bf16(fpz, *(const bf16x8*)(wir + k), air, 0, 0, 0);
        aiz = __builtin_amdgcn_mfma_f32_16x16x32_bf16(fpz, *(const bf16x8*)(wiz + k), aiz, 0, 0, 0);
        ain = __builtin_amdgcn_mfma_f32_16x16x32_bf16(fpz, *(const bf16x8*)(win + k), ain, 0, 0, 0);
        ahr = __builtin_amdgcn_mfma_f32_16x16x32_bf16(fh,  *(const bf16x8*)(whr + k), ahr, 0, 0, 0);
        ahz = __builtin_amdgcn_mfma_f32_16x16x32_bf16(fh,  *(const bf16x8*)(whz + k), ahz, 0, 0, 0);
        ahn = __builtin_amdgcn_mfma_f32_16x16x32_bf16(fh,  *(const bf16x8*)(whn + k), ahn, 0, 0, 0);
    }
    int col = lane & 15, rq = (lane >> 4) * 4;
    int j = jt + col;
    float br = bih[j], bz = bih[1024 + j], bn = bih[2048 + j];
    float cr = bhh[j], cz = bhh[1024 + j], cn = bhh[2048 + j];
    #pragma unroll
    for (int i = 0; i < 4; i++) {
        int m = mt + rq + i;
        int xb = x[m * SS + t];
        const float* gp = gipx + xb * 3072;
        float gir = air[i] + gp[j] + br;
        float giz = aiz[i] + gp[1024 + j] + bz;
        float gin = ain[i] + gp[2048 + j] + bn;
        float ghr = ahr[i] + cr;
        float ghz = ahz[i] + cz;
        float ghn = ahn[i] + cn;
        float r  = sigmoid_(gir + ghr);
        float zg = sigmoid_(giz + ghz);
        float nn = tanhf(gin + r * ghn);
        float hv = (1.f - zg) * nn + zg * h_old[m * HH + j];
        h_new[m * HH + j] = hv;
        hb_new[m * HH + j] = (__bf16)hv;
    }
}

// Tail: pri sample -> zbuf
__global__ __launch_bounds__(256) void k_tailsample(const __bf16* __restrict__ A,
                                                    const __bf16* __restrict__ W,
                                                    const float* __restrict__ pb2,
                                                    const float* __restrict__ eps512,
                                                    __bf16* __restrict__ zbuf) {
    int z0 = blockIdx.x * 64, m0 = blockIdx.y * 32;
    int w = threadIdx.x >> 6, lane = threadIdx.x & 63;
    int mt = m0 + (w & 1) * 16, nt = z0 + (w >> 1) * 32;
    f32x4 acc[2] = {{0.f,0.f,0.f,0.f},{0.f,0.f,0.f,0.f}};
    gemm_rowtile<2>(A + mt * HH, HH, W + nt * HH, HH, HH, acc);
    int col = lane & 15, rq = (lane >> 4) * 4;
    #pragma unroll
    for (int tt = 0; tt < 2; tt++) {
        int z = nt + tt * 16 + col;
        float b = pb2[z];
        #pragma unroll
        for (int i = 0; i < 4; i++) {
            int m = mt + rq + i;
            float pri = acc[tt][i] + b;
            float ps = softplus_(pri);
            zbuf[m * ZZ + z] = (__bf16)(eps512[m * ZZ + z] * ps + pri);
        }
    }
}

// cat[pz | h] bf16 [256, 2048]
__global__ void k_cat(const __bf16* __restrict__ pz, const __bf16* __restrict__ hb,
                      __bf16* __restrict__ cat) {
    int i = blockIdx.x * 256 + threadIdx.x;  // 256*2048
    int m = i >> 11, c = i & 2047;
    cat[i] = (c < 1024) ? pz[m * HH + c] : hb[m * HH + (c - 1024)];
}

extern "C" void kernel_launch(void* const* d_in, const int* in_sizes, int n_in,
                              void* d_out, int out_size, void* d_ws, size_t ws_size,
                              hipStream_t stream) {
    const int*   x       = (const int*)d_in[0];
    const float* h0      = (const float*)d_in[1];
    const float* eps     = (const float*)d_in[2];
    const float* phi_x_w = (const float*)d_in[3];
    const float* phi_x_b = (const float*)d_in[4];
    const float* enc_w1  = (const float*)d_in[5];
    const float* enc_b1  = (const float*)d_in[6];
    const float* enc_w2  = (const float*)d_in[7];
    const float* enc_b2  = (const float*)d_in[8];
    const float* pri_w1  = (const float*)d_in[9];
    const float* pri_b1  = (const float*)d_in[10];
    const float* pri_w2  = (const float*)d_in[11];
    const float* pri_b2  = (const float*)d_in[12];
    const float* phi_z_w = (const float*)d_in[13];
    const float* phi_z_b = (const float*)d_in[14];
    const float* dec_w   = (const float*)d_in[15];
    const float* dec_b   = (const float*)d_in[16];
    const float* act_w   = (const float*)d_in[17];
    const float* act_b   = (const float*)d_in[18];
    const float* gru_wih = (const float*)d_in[19];
    const float* gru_whh = (const float*)d_in[20];
    const float* gru_bih = (const float*)d_in[21];
    const float* gru_bhh = (const float*)d_in[22];

    char* p = (char*)d_ws;
    auto alloc = [&](size_t bytes) { char* r = p; p += (bytes + 255) & ~(size_t)255; return r; };

    __bf16* WA    = (__bf16*)alloc(2048 * 1024 * 2);  // enc_w1 h-half | pri_w1
    __bf16* W2    = (__bf16*)alloc(512 * 1024 * 2);   // enc_w2 | pri_w2
    __bf16* WPZ   = (__bf16*)alloc(1024 * 256 * 2);   // phi_z_w
    __bf16* WIH   = (__bf16*)alloc(3072 * 1024 * 2);  // gru_wih pz-half
    __bf16* WHH   = (__bf16*)alloc(3072 * 1024 * 2);  // gru_whh
    __bf16* WDEC  = (__bf16*)alloc(1024 * 2048 * 2);  // dec_w
    __bf16* WACT  = (__bf16*)alloc(64 * 1024 * 2);    // act_w
    float*  px    = (float*)alloc(64 * 1024 * 4);
    float*  encpx = (float*)alloc(64 * 1024 * 4);
    float*  gipx  = (float*)alloc(64 * 3072 * 4);
    float*  hf[2]; hf[0] = (float*)alloc(BB * HH * 4); hf[1] = (float*)alloc(BB * HH * 4);
    __bf16* hb[2]; hb[0] = (__bf16*)alloc(BB * HH * 2); hb[1] = (__bf16*)alloc(BB * HH * 2);
    __bf16* hidcat = (__bf16*)alloc(BB * 2048 * 2);
    __bf16* zbuf   = (__bf16*)alloc(BB * ZZ * 2);
    __bf16* pzbuf  = (__bf16*)alloc(BB * HH * 2);
    __bf16* tailhid = (__bf16*)alloc(BB * HH * 2);
    __bf16* decbuf  = (__bf16*)alloc(BB * HH * 2);
    float*  kld    = (float*)alloc(256);

    auto pack = [&](const float* src, int src_ld, int off, __bf16* dst, int rows, int cols) {
        int total = rows * cols;
        k_pack<<<(total + 255) / 256, 256, 0, stream>>>(src, src_ld, off, dst, cols, total);
    };

    k_zero<<<1, 1, 0, stream>>>(kld);
    pack(enc_w1, 2048, 1024, WA, 1024, 1024);
    pack(pri_w1, 1024, 0, WA + 1024 * 1024, 1024, 1024);
    pack(enc_w2, 1024, 0, W2, 256, 1024);
    pack(pri_w2, 1024, 0, W2 + 256 * 1024, 256, 1024);
    pack(phi_z_w, 256, 0, WPZ, 1024, 256);
    pack(gru_wih, 2048, 1024, WIH, 3072, 1024);
    pack(gru_whh, 1024, 0, WHH, 3072, 1024);
    pack(dec_w, 2048, 0, WDEC, 1024, 2048);
    pack(act_w, 1024, 0, WACT, 64, 1024);
    pack(h0, 1024, 0, hb[0], 256, 1024);
    k_copyf<<<(BB * HH + 255) / 256, 256, 0, stream>>>(h0, hf[0], BB * HH);
    k_px<<<(64 * 1024) / 256, 256, 0, stream>>>(phi_x_w, phi_x_b, px);
    k_tables<<<1024, 256, 0, stream>>>(enc_w1, gru_wih, px, encpx, gipx);

    for (int t = 0; t < SS; t++) {
        int cur = t & 1, nxt = cur ^ 1;
        k_phaseA<<<dim3(32, 8), 256, 0, stream>>>(hb[cur], WA, enc_b1, pri_b1, encpx, x, t, hidcat);
        k_phaseB<<<dim3(8, 8), 256, 0, stream>>>(hidcat, W2, enc_b2, pri_b2,
                                                 eps + (size_t)t * BB * ZZ, zbuf, kld);
        k_gemm<true, true><<<dim3(16, 8), 256, 0, stream>>>(zbuf, ZZ, WPZ, ZZ, phi_z_b,
                                                            pzbuf, HH, ZZ);
        k_phaseD<<<dim3(32, 8), 256, 0, stream>>>(pzbuf, hb[cur], WIH, WHH, gipx,
                                                  gru_bih, gru_bhh, x, t,
                                                  hf[cur], hf[nxt], hb[nxt]);
    }
    // final h is in buffer 0 (after t=511, nxt = 0)
    k_gemm<true, true><<<dim3(16, 8), 256, 0, stream>>>(hb[0], HH, WA + 1024 * 1024, HH,
                                                        pri_b1, tailhid, HH, HH);
    k_tailsample<<<dim3(4, 8), 256, 0, stream>>>(tailhid, W2 + 256 * 1024, pri_b2,
                                                 eps + (size_t)SS * BB * ZZ, zbuf);
    k_gemm<true, true><<<dim3(16, 8), 256, 0, stream>>>(zbuf, ZZ, WPZ, ZZ, phi_z_b,
                                                        pzbuf, HH, ZZ);
    k_cat<<<(BB * 2048) / 256, 256, 0, stream>>>(pzbuf, hb[0], hidcat);
    k_gemm<true, true><<<dim3(16, 8), 256, 0, stream>>>(hidcat, 2048, WDEC, 2048,
                                                        dec_b, decbuf, HH, 2048);
    k_gemm<false, false><<<dim3(1, 8), 256, 0, stream>>>(decbuf, HH, WACT, HH,
                                                         act_b, d_out, AA, HH);
    k_finkld<<<1, 1, 0, stream>>>(kld, (float*)d_out + BB * AA);
}